// Round 1
// 626.603 us; speedup vs baseline: 1.0715x; 1.0715x over previous
//
#include <hip/hip_runtime.h>
#include <hip/hip_bf16.h>
#include <stdint.h>

#define NTOK 8192
#define DM   1024
#define DFF  4096
#define NE   8

typedef __bf16 bf16x8 __attribute__((ext_vector_type(8)));
typedef short  short8 __attribute__((ext_vector_type(8)));
typedef float  floatx4 __attribute__((ext_vector_type(4)));

// ---- workspace layout (bytes) ----
#define WS_CNT   0                            // 8 ints
#define WS_OFF   64                           // 8 ints
#define WS_EIDX  1024                         // NTOK ints
#define WS_PERM  (WS_EIDX + NTOK * 4)         // NTOK ints
#define WS_XPERM (WS_PERM + NTOK * 4)         // (NTOK+128) x DM bf16
#define WS_HPERM (WS_XPERM + (size_t)(NTOK + 128) * DM * 2)   // (NTOK+128) x DFF bf16
#define WS_UPWT  (WS_HPERM + (size_t)(NTOK + 128) * DFF * 2)  // [E][DFF][DM] bf16 (transposed)
#define WS_DWT   (WS_UPWT + (size_t)NE * DM * DFF * 2)        // [E][DM][DFF] bf16 (transposed)

__device__ __forceinline__ unsigned short f2bf(float f) {
  union { float f; unsigned u; } v; v.f = f;
  return (unsigned short)((v.u + 0x7FFFu + ((v.u >> 16) & 1u)) >> 16);
}

__device__ __forceinline__ float f4get(const float4& v, int i) {
  return i == 0 ? v.x : i == 1 ? v.y : i == 2 ? v.z : v.w;
}

// async global->LDS, 16B per lane. LDS dest is wave-uniform base + lane*16.
__device__ __forceinline__ void gload_lds16(const void* g, void* l) {
  __builtin_amdgcn_global_load_lds(
      (const __attribute__((address_space(1))) unsigned int*)g,
      (__attribute__((address_space(3))) unsigned int*)l, 16, 0, 0);
}

// ---- weight transpose+convert: W fp32 [E][K][N] -> Wt bf16 [E][N][K] ----
// grid: (N/64, K/64, E), 256 threads. 64x64 tile via LDS.
__global__ __launch_bounds__(256) void wconv_kernel(
    const float* __restrict__ W, unsigned short* __restrict__ Wt,
    int K, int N) {
  __shared__ __attribute__((aligned(16))) unsigned short s[64][72];
  int n0 = blockIdx.x * 64;
  int k0 = blockIdx.y * 64;
  const float* Wp = W + (size_t)blockIdx.z * K * N + (size_t)k0 * N + n0;
  int t = threadIdx.x;
  int kr = t >> 4;            // 0..15
  int nc = (t & 15) * 4;      // 0..60
#pragma unroll
  for (int q = 0; q < 4; ++q) {
    float4 v = *(const float4*)(Wp + (size_t)(q * 16 + kr) * N + nc);
    s[nc + 0][q * 16 + kr] = f2bf(v.x);
    s[nc + 1][q * 16 + kr] = f2bf(v.y);
    s[nc + 2][q * 16 + kr] = f2bf(v.z);
    s[nc + 3][q * 16 + kr] = f2bf(v.w);
  }
  __syncthreads();
  int nr = t >> 2;            // 0..63
  int kc = (t & 3) * 16;      // 0,16,32,48
  unsigned short* dst = Wt + (size_t)blockIdx.z * N * K + (size_t)(n0 + nr) * K + k0 + kc;
  *(uint4*)dst       = *(const uint4*)&s[nr][kc];
  *(uint4*)(dst + 8) = *(const uint4*)&s[nr][kc + 8];
}

// one wave per token: fp32 logits, argmax (first max), one-hot out, eidx. NO atomics.
__global__ __launch_bounds__(256) void gate_kernel(
    const float* __restrict__ x, const float* __restrict__ gW,
    const float* __restrict__ gb, float* __restrict__ gate_out,
    int* __restrict__ eidx) {
  int wave = threadIdx.x >> 6;
  int lane = threadIdx.x & 63;
  int t = blockIdx.x * 4 + wave;
  const float4* xr = (const float4*)(x + (size_t)t * DM + lane * 16);
  float acc[8] = {0, 0, 0, 0, 0, 0, 0, 0};
#pragma unroll
  for (int q = 0; q < 4; ++q) {
    float4 xv = xr[q];
    int kbase = lane * 16 + q * 4;
#pragma unroll
    for (int d = 0; d < 4; ++d) {
      float xs = f4get(xv, d);
      const float4* g4 = (const float4*)(gW + (size_t)(kbase + d) * NE);
      float4 g0 = g4[0], g1 = g4[1];
      acc[0] += xs * g0.x; acc[1] += xs * g0.y;
      acc[2] += xs * g0.z; acc[3] += xs * g0.w;
      acc[4] += xs * g1.x; acc[5] += xs * g1.y;
      acc[6] += xs * g1.z; acc[7] += xs * g1.w;
    }
  }
#pragma unroll
  for (int off = 32; off > 0; off >>= 1) {
#pragma unroll
    for (int e = 0; e < 8; ++e) acc[e] += __shfl_down(acc[e], off);
  }
  if (lane == 0) {
    float best = acc[0] + gb[0];
    int bi = 0;
#pragma unroll
    for (int e = 1; e < 8; ++e) {
      float v = acc[e] + gb[e];
      if (v > best) { best = v; bi = e; }
    }
#pragma unroll
    for (int e = 0; e < 8; ++e) gate_out[(size_t)t * NE + e] = (e == bi) ? 1.0f : 0.0f;
    eidx[t] = bi;
  }
}

// single block, 1024 threads: stable counting-sort ranks via packed 16-bit scan.
__global__ __launch_bounds__(1024) void rank_kernel(
    const int* __restrict__ eidx, int* __restrict__ counts,
    int* __restrict__ offs, int* __restrict__ perm) {
  __shared__ unsigned long long sa[1024], sb[1024];
  int tid = threadIdx.x;
  int e8[8];
  unsigned long long ca = 0, cb = 0;
#pragma unroll
  for (int j = 0; j < 8; ++j) {
    int e = eidx[tid * 8 + j];
    e8[j] = e;
    if (e < 4) ca += 1ull << (16 * e);
    else       cb += 1ull << (16 * (e - 4));
  }
  sa[tid] = ca; sb[tid] = cb;
  __syncthreads();
  for (int off = 1; off < 1024; off <<= 1) {
    unsigned long long ta = 0, tb = 0;
    if (tid >= off) { ta = sa[tid - off]; tb = sb[tid - off]; }
    __syncthreads();
    sa[tid] += ta; sb[tid] += tb;
    __syncthreads();
  }
  unsigned long long tot_a = sa[1023], tot_b = sb[1023];
  int cnt_e[8];
#pragma unroll
  for (int e = 0; e < 4; ++e) cnt_e[e] = (int)((tot_a >> (16 * e)) & 0xFFFF);
#pragma unroll
  for (int e = 0; e < 4; ++e) cnt_e[e + 4] = (int)((tot_b >> (16 * e)) & 0xFFFF);
  int off_e[8]; int s = 0;
#pragma unroll
  for (int e = 0; e < 8; ++e) { off_e[e] = s; s += cnt_e[e]; }
  if (tid < 8) { counts[tid] = cnt_e[tid]; offs[tid] = off_e[tid]; }
  unsigned long long ia = sa[tid] - ca, ib = sb[tid] - cb;   // exclusive starts
  int run[8];
#pragma unroll
  for (int e = 0; e < 4; ++e) run[e] = (int)((ia >> (16 * e)) & 0xFFFF);
#pragma unroll
  for (int e = 0; e < 4; ++e) run[e + 4] = (int)((ib >> (16 * e)) & 0xFFFF);
#pragma unroll
  for (int j = 0; j < 8; ++j) {
    int e = e8[j];
    int pos = off_e[e] + run[e]++;
    perm[pos] = tid * 8 + j;
  }
}

// one wave per DEST row: gather x[perm[p]] -> bf16 xperm[p]. No atomics.
__global__ __launch_bounds__(256) void scatter_data_kernel(
    const float* __restrict__ x, const int* __restrict__ perm,
    unsigned short* __restrict__ xperm) {
  int wave = threadIdx.x >> 6, lane = threadIdx.x & 63;
  int p = blockIdx.x * 4 + wave;
  int t = perm[p];
  const float4* xr = (const float4*)(x + (size_t)t * DM);
#pragma unroll
  for (int q = 0; q < 4; ++q) {
    float4 v = xr[q * 64 + lane];
    uint2 pk;
    pk.x = (unsigned)f2bf(v.x) | ((unsigned)f2bf(v.y) << 16);
    pk.y = (unsigned)f2bf(v.z) | ((unsigned)f2bf(v.w) << 16);
    *(uint2*)(xperm + (size_t)p * DM + q * 256 + lane * 4) = pk;
  }
}

// ---- up GEMM: h = relu(x_perm @ up_W[e] + up_b[e]) -> bf16 h_perm ----
// m97 structure: 128x128 tile, BK=32, global_load_lds both operands, linear LDS.
// 1D grid 16384 = 8 e * 32 nt * 64 mt (mt fastest), bijective XCD swizzle:
// one expert per XCD -> B-stripes + A-slab L2-resident.
__global__ __launch_bounds__(256) void up_gemm_kernel(
    const unsigned short* __restrict__ xperm,
    const unsigned short* __restrict__ upWt,   // [E][DFF][DM] bf16
    const float* __restrict__ upB,
    const int* __restrict__ counts, const int* __restrict__ offs,
    unsigned short* __restrict__ hperm) {
  const int nwg = NE * 32 * 64;                // 16384
  int orig = blockIdx.x;
  int wg = (orig & 7) * (nwg >> 3) + (orig >> 3);
  int e  = wg >> 11;          // / (32*64)
  int r  = wg & 2047;
  int nt = r >> 6;            // 0..31
  int mt = r & 63;            // 0..63 (mt fastest: consecutive wgs share B-stripe)
  int cnt = counts[e];
  if (mt * 128 >= cnt) return;
  int row0 = offs[e] + mt * 128;
  int rows_valid = cnt - mt * 128; if (rows_valid > 128) rows_valid = 128;
  int n0 = nt * 128;

  __shared__ __attribute__((aligned(16))) unsigned short sA[128 * 32];
  __shared__ __attribute__((aligned(16))) unsigned short sB[128 * 32];

  int tid = threadIdx.x;
  int wave = tid >> 6, lane = tid & 63;
  int wm = (wave >> 1) * 64, wn = (wave & 1) * 64;

  // staging: wave w owns rows [w*32, w*32+32); lane covers row w*32+(lane>>2) (+16), col (lane&3)*8
  int srow = wave * 32 + (lane >> 2);
  int scol = (lane & 3) * 8;
  const unsigned short* gA0 = xperm + (size_t)(row0 + srow) * DM + scol;
  const unsigned short* gA1 = gA0 + 16 * DM;
  const unsigned short* gB0 = upWt + (size_t)e * DFF * DM + (size_t)(n0 + srow) * DM + scol;
  const unsigned short* gB1 = gB0 + 16 * DM;
  unsigned short* lA0 = sA + wave * 1024;      // wave-uniform LDS base
  unsigned short* lA1 = lA0 + 512;
  unsigned short* lB0 = sB + wave * 1024;
  unsigned short* lB1 = lB0 + 512;

  floatx4 acc[4][4];
#pragma unroll
  for (int i = 0; i < 4; ++i)
#pragma unroll
    for (int j = 0; j < 4; ++j) acc[i][j] = (floatx4){0.f, 0.f, 0.f, 0.f};

  for (int k0 = 0; k0 < DM; k0 += 32) {
    __syncthreads();
    gload_lds16(gA0 + k0, lA0);
    gload_lds16(gA1 + k0, lA1);
    gload_lds16(gB0 + k0, lB0);
    gload_lds16(gB1 + k0, lB1);
    __syncthreads();
    bf16x8 a[4], b[4];
#pragma unroll
    for (int i = 0; i < 4; ++i)
      a[i] = *(const bf16x8*)(sA + (wm + i * 16 + (lane & 15)) * 32 + (lane >> 4) * 8);
#pragma unroll
    for (int j = 0; j < 4; ++j)
      b[j] = *(const bf16x8*)(sB + (wn + j * 16 + (lane & 15)) * 32 + (lane >> 4) * 8);
#pragma unroll
    for (int i = 0; i < 4; ++i)
#pragma unroll
      for (int j = 0; j < 4; ++j)
        acc[i][j] = __builtin_amdgcn_mfma_f32_16x16x32_bf16(a[i], b[j], acc[i][j], 0, 0, 0);
  }

  const float* ub = upB + (size_t)e * DFF;
#pragma unroll
  for (int i = 0; i < 4; ++i) {
#pragma unroll
    for (int r2 = 0; r2 < 4; ++r2) {
      int rl = wm + i * 16 + (lane >> 4) * 4 + r2;
      if (rl < rows_valid) {
        size_t rowg = (size_t)(row0 + rl) * DFF;
#pragma unroll
        for (int j = 0; j < 4; ++j) {
          int col = n0 + wn + j * 16 + (lane & 15);
          float v = acc[i][j][r2] + ub[col];
          v = v > 0.f ? v : 0.f;
          hperm[rowg + col] = f2bf(v);
        }
      }
    }
  }
}

// ---- down GEMM: out[token] = h_perm @ down_W[e] + down_b[e] (fp32 scatter) ----
__global__ __launch_bounds__(256) void down_gemm_kernel(
    const unsigned short* __restrict__ hperm,
    const unsigned short* __restrict__ dWt,    // [E][DM][DFF] bf16
    const float* __restrict__ dB,
    const int* __restrict__ counts, const int* __restrict__ offs,
    const int* __restrict__ perm, float* __restrict__ out) {
  const int nwg = NE * 8 * 64;                 // 4096
  int orig = blockIdx.x;
  int wg = (orig & 7) * (nwg >> 3) + (orig >> 3);
  int e  = wg >> 9;           // / (8*64)
  int r  = wg & 511;
  int nt = r >> 6;            // 0..7
  int mt = r & 63;
  int cnt = counts[e];
  if (mt * 128 >= cnt) return;
  int row0 = offs[e] + mt * 128;
  int rows_valid = cnt - mt * 128; if (rows_valid > 128) rows_valid = 128;
  int n0 = nt * 128;

  __shared__ __attribute__((aligned(16))) unsigned short sA[128 * 32];
  __shared__ __attribute__((aligned(16))) unsigned short sB[128 * 32];

  int tid = threadIdx.x;
  int wave = tid >> 6, lane = tid & 63;
  int wm = (wave >> 1) * 64, wn = (wave & 1) * 64;

  int srow = wave * 32 + (lane >> 2);
  int scol = (lane & 3) * 8;
  const unsigned short* gA0 = hperm + (size_t)(row0 + srow) * DFF + scol;
  const unsigned short* gA1 = gA0 + 16 * DFF;
  const unsigned short* gB0 = dWt + (size_t)e * DM * DFF + (size_t)(n0 + srow) * DFF + scol;
  const unsigned short* gB1 = gB0 + 16 * DFF;
  unsigned short* lA0 = sA + wave * 1024;
  unsigned short* lA1 = lA0 + 512;
  unsigned short* lB0 = sB + wave * 1024;
  unsigned short* lB1 = lB0 + 512;

  floatx4 acc[4][4];
#pragma unroll
  for (int i = 0; i < 4; ++i)
#pragma unroll
    for (int j = 0; j < 4; ++j) acc[i][j] = (floatx4){0.f, 0.f, 0.f, 0.f};

  for (int k0 = 0; k0 < DFF; k0 += 32) {
    __syncthreads();
    gload_lds16(gA0 + k0, lA0);
    gload_lds16(gA1 + k0, lA1);
    gload_lds16(gB0 + k0, lB0);
    gload_lds16(gB1 + k0, lB1);
    __syncthreads();
    bf16x8 a[4], b[4];
#pragma unroll
    for (int i = 0; i < 4; ++i)
      a[i] = *(const bf16x8*)(sA + (wm + i * 16 + (lane & 15)) * 32 + (lane >> 4) * 8);
#pragma unroll
    for (int j = 0; j < 4; ++j)
      b[j] = *(const bf16x8*)(sB + (wn + j * 16 + (lane & 15)) * 32 + (lane >> 4) * 8);
#pragma unroll
    for (int i = 0; i < 4; ++i)
#pragma unroll
      for (int j = 0; j < 4; ++j)
        acc[i][j] = __builtin_amdgcn_mfma_f32_16x16x32_bf16(a[i], b[j], acc[i][j], 0, 0, 0);
  }

  const float* db = dB + (size_t)e * DM;
#pragma unroll
  for (int i = 0; i < 4; ++i) {
#pragma unroll
    for (int r2 = 0; r2 < 4; ++r2) {
      int rl = wm + i * 16 + (lane >> 4) * 4 + r2;
      if (rl < rows_valid) {
        int token = perm[row0 + rl];
        size_t og = (size_t)token * DM;
#pragma unroll
        for (int j = 0; j < 4; ++j) {
          int col = n0 + wn + j * 16 + (lane & 15);
          out[og + col] = acc[i][j][r2] + db[col];
        }
      }
    }
  }
}

extern "C" void kernel_launch(void* const* d_in, const int* in_sizes, int n_in,
                              void* d_out, int out_size, void* d_ws, size_t ws_size,
                              hipStream_t stream) {
  const float* x   = (const float*)d_in[0];
  const float* gW  = (const float*)d_in[1];
  const float* gb  = (const float*)d_in[2];
  const float* upW = (const float*)d_in[3];
  const float* upB = (const float*)d_in[4];
  const float* dW  = (const float*)d_in[5];
  const float* dB  = (const float*)d_in[6];
  float* out      = (float*)d_out;
  float* gate_out = out + (size_t)NTOK * DM;

  char* ws = (char*)d_ws;
  int* cnt  = (int*)(ws + WS_CNT);
  int* off  = (int*)(ws + WS_OFF);
  int* eidx = (int*)(ws + WS_EIDX);
  int* perm = (int*)(ws + WS_PERM);
  unsigned short* xperm = (unsigned short*)(ws + WS_XPERM);
  unsigned short* hperm = (unsigned short*)(ws + WS_HPERM);
  unsigned short* upWt  = (unsigned short*)(ws + WS_UPWT);
  unsigned short* dWt   = (unsigned short*)(ws + WS_DWT);

  // weight transpose+convert (fp32 [K][N] -> bf16 [N][K])
  wconv_kernel<<<dim3(DFF / 64, DM / 64, NE), 256, 0, stream>>>(upW, upWt, DM, DFF);
  wconv_kernel<<<dim3(DM / 64, DFF / 64, NE), 256, 0, stream>>>(dW, dWt, DFF, DM);

  gate_kernel<<<NTOK / 4, 256, 0, stream>>>(x, gW, gb, gate_out, eidx);
  rank_kernel<<<1, 1024, 0, stream>>>(eidx, cnt, off, perm);
  scatter_data_kernel<<<NTOK / 4, 256, 0, stream>>>(x, perm, xperm);
  up_gemm_kernel<<<NE * 32 * 64, 256, 0, stream>>>(xperm, upWt, upB, cnt, off, hperm);
  down_gemm_kernel<<<NE * 8 * 64, 256, 0, stream>>>(hperm, dWt, dB, cnt, off, perm, out);
}